// Round 8
// baseline (361.921 us; speedup 1.0000x reference)
//
#include <hip/hip_runtime.h>
#include <hip/hip_bf16.h>
#include <math.h>

#define T_TOK 4096
#define H_DIM 2048
#define NH 16
#define NKV 8
#define HD 128
#define QS (NH * HD)        // 2048
#define KVS (NKV * HD)      // 1024
#define QKV_W (QS + 2*KVS)  // 4096
// SCALE * log2(e): Q pre-scaled so softmax runs in exp2 domain
#define QSCALE (0.08838834764831845f * 1.4426950408889634f)
#define EPS 1e-6f

typedef short short8 __attribute__((ext_vector_type(8)));
typedef short short4v __attribute__((ext_vector_type(4)));
typedef float floatx4 __attribute__((ext_vector_type(4)));
typedef float floatx16 __attribute__((ext_vector_type(16)));
typedef unsigned int uint2v __attribute__((ext_vector_type(2)));

#if __has_builtin(__builtin_amdgcn_exp2f)
#define EXP2(x) __builtin_amdgcn_exp2f(x)
#else
#define EXP2(x) exp2f(x)
#endif

__device__ __forceinline__ unsigned short f2bf(float f) {
    unsigned int u = __float_as_uint(f);
    unsigned int r = (u + 0x7FFFu + ((u >> 16) & 1u)) >> 16;   // RNE
    return (unsigned short)r;
}
__device__ __forceinline__ float bf2f(unsigned short u) {
    unsigned int v = ((unsigned int)u) << 16;
    return __uint_as_float(v);
}
// packed f32x2 -> bf16x2
__device__ __forceinline__ unsigned int pk2(float a, float b) {
    union { __hip_bfloat162 h; unsigned int u; } c;
    c.h = __float22bfloat162_rn(make_float2(a, b));
    return c.u;
}

// async global->LDS 16B: LDS dest is wave-uniform base + lane*16
__device__ __forceinline__ void gload_lds16(const unsigned short* g, unsigned short* l) {
    __builtin_amdgcn_global_load_lds(
        (const __attribute__((address_space(1))) unsigned int*)(const void*)g,
        (__attribute__((address_space(3))) unsigned int*)(void*)l, 16, 0, 0);
}

// ---------------- f32 -> bf16 flat convert ---------------------------------
__global__ __launch_bounds__(256) void cvt_bf16(const float* __restrict__ in,
                                                unsigned short* __restrict__ out) {
    int idx = (blockIdx.x * 256 + threadIdx.x) * 8;
    float4 v0 = *(const float4*)&in[idx];
    float4 v1 = *(const float4*)&in[idx + 4];
    short8 t;
    t[0] = (short)f2bf(v0.x); t[1] = (short)f2bf(v0.y);
    t[2] = (short)f2bf(v0.z); t[3] = (short)f2bf(v0.w);
    t[4] = (short)f2bf(v1.x); t[5] = (short)f2bf(v1.y);
    t[6] = (short)f2bf(v1.z); t[7] = (short)f2bf(v1.w);
    *(short8*)&out[idx] = t;
}

// ------------- f32 [K][N] -> bf16 [N][K] transpose+convert -----------------
__global__ __launch_bounds__(256) void cvt_transpose(const float* __restrict__ in,
                                                     unsigned short* __restrict__ out,
                                                     int K, int N) {
    __shared__ __align__(16) unsigned short t[64][72];
    const int tid = threadIdx.x;
    const int n0 = blockIdx.x * 64, k0 = blockIdx.y * 64;
    const int r = tid >> 4, c4 = (tid & 15) * 4;
    #pragma unroll
    for (int i = 0; i < 4; ++i) {
        int kk = r + 16 * i;
        float4 v = *(const float4*)&in[(size_t)(k0 + kk) * N + n0 + c4];
        t[c4 + 0][kk] = f2bf(v.x); t[c4 + 1][kk] = f2bf(v.y);
        t[c4 + 2][kk] = f2bf(v.z); t[c4 + 3][kk] = f2bf(v.w);
    }
    __syncthreads();
    const int n = tid >> 2, c8 = (tid & 3) * 16;
    short8 a = *(const short8*)&t[n][c8];
    short8 b = *(const short8*)&t[n][c8 + 8];
    *(short8*)&out[(size_t)(n0 + n) * K + k0 + c8] = a;
    *(short8*)&out[(size_t)(n0 + n) * K + k0 + c8 + 8] = b;
}

// ====== 256xBN pipelined bf16 GEMM: C[M,N] = A[M,K] @ Bt[N,K]^T ============
// BK=64, 2 whole-K-tile LDS buffers; one covered vmcnt(0) + one barrier per
// K-tile; setprio; XOR chunk swizzle both-sides; XCD-chunked block swizzle.
template<bool C_BF16, int BN>
__global__ __launch_bounds__(512, 2) void gemm8p(const unsigned short* __restrict__ A, int lda,
                                                 const unsigned short* __restrict__ Bt, int ldb,
                                                 void* __restrict__ Cptr, int ldc, int K, int nbx) {
    constexpr int LDSTILE = 16384 + BN * 64;      // ushorts: A 256x64 + B BNx64
    constexpr int NFRAG = BN / 64;                // B frags per wave per kk
    __shared__ __align__(16) unsigned short lds[2 * LDSTILE];
    const int tid  = threadIdx.x;
    const int wave = tid >> 6, lane = tid & 63;
    const int quad = lane >> 4, l16 = lane & 15;
    const int wm = wave >> 2, wn = wave & 3;

    // XCD-chunked bijective swizzle (gridDim.x % 8 == 0)
    const int cpx = gridDim.x >> 3;
    const int swzb = (blockIdx.x & 7) * cpx + (blockIdx.x >> 3);
    const int by = swzb / nbx, bx = swzb % nbx;
    const int bm = by * 256, bn = bx * BN;

    // staging invariants: per 128-row half-panel, 1024 chunks, 2 per thread
    const int ch0 = wave * 64 + lane, ch1 = 512 + ch0;
    const int r0 = ch0 >> 3, gc0 = ((ch0 & 7) ^ (r0 & 7)) * 8;
    const int r1 = ch1 >> 3, gc1 = ((ch1 & 7) ^ (r1 & 7)) * 8;
    const unsigned du0 = (unsigned)(wave * 64) * 8;
    const unsigned du1 = (unsigned)(512 + wave * 64) * 8;

    auto stageP = [&](const unsigned short* P, int bp, int ld,
                      unsigned short* dstbase, int rhalf, int kt) {
        unsigned short* dst = dstbase + rhalf * 64;
        gload_lds16(P + (size_t)(bp + rhalf + r0) * ld + kt * 64 + gc0, dst + du0);
        gload_lds16(P + (size_t)(bp + rhalf + r1) * ld + kt * 64 + gc1, dst + du1);
    };
    auto stage = [&](int kt, int buf) {                 // whole tile: A + B
        unsigned short* ab = &lds[buf * LDSTILE];
        unsigned short* bb = ab + 16384;
        stageP(A, bm, lda, ab, 0, kt);
        stageP(A, bm, lda, ab, 128, kt);
        stageP(Bt, bn, ldb, bb, 0, kt);
        if (BN == 256) stageP(Bt, bn, ldb, bb, 128, kt);
    };

    floatx4 acc[8][NFRAG] = {};
    const int arowb = wm * 128 + l16;
    const int browb = wn * (BN / 4) + l16;
    const int sw = l16 & 7;

    auto compute = [&](int buf) {
        const unsigned short* ab = &lds[buf * LDSTILE];
        const unsigned short* bb = ab + 16384;
        __builtin_amdgcn_s_setprio(1);
        #pragma unroll
        for (int kk = 0; kk < 2; ++kk) {
            const int sl = ((kk * 4 + quad) ^ sw) * 8;
            short8 bfr[NFRAG];
            #pragma unroll
            for (int ni = 0; ni < NFRAG; ++ni)
                bfr[ni] = *(const short8*)&bb[(browb + ni * 16) * 64 + sl];
            #pragma unroll
            for (int mh = 0; mh < 2; ++mh) {
                short8 afr[4];
                #pragma unroll
                for (int mi = 0; mi < 4; ++mi)
                    afr[mi] = *(const short8*)&ab[(arowb + (mh * 4 + mi) * 16) * 64 + sl];
                #pragma unroll
                for (int mi = 0; mi < 4; ++mi)
                    #pragma unroll
                    for (int ni = 0; ni < NFRAG; ++ni)
                        acc[mh * 4 + mi][ni] =
                            __builtin_amdgcn_mfma_f32_16x16x32_bf16(afr[mi], bfr[ni], acc[mh * 4 + mi][ni], 0, 0, 0);
            }
        }
        __builtin_amdgcn_s_setprio(0);
    };

    const int NT = K >> 6;                        // K-tiles of 64
    stage(0, 0);
    int cur = 0;
    for (int kt = 0; kt < NT; ++kt) {
        asm volatile("s_waitcnt vmcnt(0)" ::: "memory");  // covered by prev tile's compute
        __builtin_amdgcn_s_barrier();
        if (kt + 1 < NT) stage(kt + 1, cur ^ 1);
        compute(cur);
        cur ^= 1;
    }

    // ---- epilogue: C[row, col]
    #pragma unroll
    for (int mi = 0; mi < 8; ++mi)
        #pragma unroll
        for (int ni = 0; ni < NFRAG; ++ni)
            #pragma unroll
            for (int r = 0; r < 4; ++r) {
                int row = bm + wm * 128 + mi * 16 + quad * 4 + r;
                int col = bn + wn * (BN / 4) + ni * 16 + l16;
                if (C_BF16)
                    ((unsigned short*)Cptr)[(size_t)row * ldc + col] = f2bf(acc[mi][ni][r]);
                else
                    ((float*)Cptr)[(size_t)row * ldc + col] = acc[mi][ni][r];
            }
}

// ============ per-head RMSNorm + RoPE; q additionally scaled by QSCALE =====
__global__ __launch_bounds__(256) void rms_rope_bf16(unsigned short* __restrict__ qkv,
                                                     const int* __restrict__ positions,
                                                     const float* __restrict__ qw,
                                                     const float* __restrict__ kw) {
    const int t = blockIdx.x;
    const int wave = threadIdx.x >> 6;
    const int lane = threadIdx.x & 63;
    const float pos = (float)positions[t];
    unsigned short* row = qkv + (size_t)t * QKV_W;
    // 1e6^(-lane/64) = exp2(-lane * log2(1e6)/64)
    const float inv_freq = exp2f(-(float)lane * (19.931568569324174f / 64.0f));
    float sv, cv;
    sincosf(pos * inv_freq, &sv, &cv);
    for (int h = wave; h < NH + NKV; h += 4) {
        unsigned short* x = row + h * HD;
        const float* w = (h < NH) ? qw : kw;
        const float hs = (h < NH) ? QSCALE : 1.0f;
        float x1 = bf2f(x[lane]);
        float x2 = bf2f(x[lane + 64]);
        float ss = x1 * x1 + x2 * x2;
        #pragma unroll
        for (int off = 32; off > 0; off >>= 1) ss += __shfl_xor(ss, off, 64);
        float r = rsqrtf(ss * (1.0f / 128.0f) + EPS) * hs;
        float n1 = x1 * r * w[lane];
        float n2 = x2 * r * w[lane + 64];
        x[lane]      = f2bf(n1 * cv - n2 * sv);
        x[lane + 64] = f2bf(n2 * cv + n1 * sv);
    }
}

// ====== KV pre-pack: per kvh, per 128-token tile, contiguous 32 KB tiles ===
// Kp tile: chunk (s, c) -> slot s*16 + (c ^ (s&7))           [s=token, c=dim/8]
// Vp tile: V^T chunk (d, cs) -> slot d*16 + (cs ^ (d&7))  (straight chunks;
// b128 reads at chunk granularity are floor-optimal like the K pattern)
__global__ __launch_bounds__(256) void kv_pack(const unsigned short* __restrict__ qkv,
                                               unsigned short* __restrict__ Kp,
                                               unsigned short* __restrict__ Vp) {
    const int tile = blockIdx.x, kvh = blockIdx.y, tid = threadIdx.x;
    const int t0 = tile * 128;
    const size_t tb = (size_t)(kvh * 32 + tile) * 16384;
    // ---- K: swizzle chunks within each row
    #pragma unroll
    for (int i = 0; i < 8; ++i) {
        int cid = i * 256 + tid;
        int s = cid >> 4, c = cid & 15;
        short8 v = *(const short8*)&qkv[(size_t)(t0 + s) * QKV_W + QS + kvh * HD + c * 8];
        *(short8*)&Kp[tb + (s * 16 + (c ^ (s & 7))) * 8] = v;
    }
    // ---- V: transpose via LDS
    __shared__ __align__(16) unsigned short Lt[128 * 136];
    #pragma unroll
    for (int i = 0; i < 8; ++i) {
        int cid = i * 256 + tid;
        int s = cid >> 4, c = cid & 15;
        short8 v = *(const short8*)&qkv[(size_t)(t0 + s) * QKV_W + QS + KVS + kvh * HD + c * 8];
        // rotated element order: lanes with different c hit different banks
        #pragma unroll
        for (int e = 0; e < 8; ++e) {
            int ee = (e + c) & 7;
            Lt[(c * 8 + ee) * 136 + s] = (unsigned short)v[ee];
        }
    }
    __syncthreads();
    #pragma unroll
    for (int i = 0; i < 8; ++i) {
        int cid = i * 256 + tid;
        int d = cid >> 4, cs = cid & 15;
        short8 v = *(const short8*)&Lt[d * 136 + cs * 8];
        *(short8*)&Vp[tb + (d * 16 + (cs ^ (d & 7))) * 8] = v;
    }
}

// ================= MFMA causal GQA flash attention (32x32 MFMA) ============
// S^T = K·Q^T via mfma_f32_32x32x16_bf16: per wave 32 q-rows, per ct2 a full
// 32s x 32t S^T block in ONE 16-reg accumulator (8 chained K=16 MFMAs).
// PV also 32x32x16: P-fragment redistribution (lane needs s=16m+8h+e) is a
// pure lane<->lane+32 exchange done with 4 permlane32_swap per ct2 (T12).
// V reads are b128 chunks -> Vp needs no half-swap.  Instruction count per
// 32-token block: 16 MFMA + 16 b128 (was 48 MFMA + 24 reads).
__global__ __launch_bounds__(256, 2) void attn_mfma(unsigned short* __restrict__ qkv,
                                                    const unsigned short* __restrict__ Kp,
                                                    const unsigned short* __restrict__ Vp) {
    __shared__ __align__(16) unsigned short Ks[128 * 128];
    __shared__ __align__(16) unsigned short Vs[128 * 128];
    const int bx = blockIdx.x;
    const int h = bx & 15, kvh = h >> 1;            // XCD = bx%8 tracks h%8
    const int g = bx >> 4;                          // 0..31
    const int qt = (g < 16) ? (31 - g) : (g - 16);  // pair sums = 31
    const int tid = threadIdx.x;
    const int wave = tid >> 6, lane = tid & 63;
    const int t5 = lane & 31, hh = lane >> 5;
    const int sw5 = t5 & 7;
    const int t0 = qt * 128;
    const int wrow0 = t0 + wave * 32;
    const int tg = wrow0 + t5;                      // this lane's q-row (col of S^T)

    // Q fragments (pre-scaled by QSCALE); B-operand of K·Q^T (32x32x16):
    // lane holds Q[t = t5][k = ks*16 + hh*8 + e]
    short8 qf2[8];
    #pragma unroll
    for (int ks = 0; ks < 8; ++ks)
        qf2[ks] = *(const short8*)&qkv[(size_t)tg * QKV_W + h * HD + ks * 16 + hh * 8];

    float l_s = 0.0f;
    floatx16 oacc[4] = {};                          // O[32t][4 x 32d]

    for (int st = 0; st <= qt; ++st) {
        const int s0 = st * 128;
        const unsigned short* kb = Kp + (size_t)(kvh * 32 + st) * 16384;
        const unsigned short* vb = Vp + (size_t)(kvh * 32 + st) * 16384;
        #pragma unroll
        for (int i = 0; i < 8; ++i) {
            int ch = i * 256 + tid;
            gload_lds16(kb + (size_t)ch * 8, Ks + (i * 256 + wave * 64) * 8);
        }
        #pragma unroll
        for (int i = 0; i < 8; ++i) {
            int ch = i * 256 + tid;
            gload_lds16(vb + (size_t)ch * 8, Vs + (i * 256 + wave * 64) * 8);
        }
        __syncthreads();   // bar1: staging visible

        const bool diag = (st == qt);
        #pragma unroll
        for (int ct2 = 0; ct2 < 4; ++ct2) {
            const int smin = s0 + ct2 * 32;
            if (diag && smin > wrow0 + 31) continue;   // wave-uniform causal skip
            // ---- S^T 32x32 block: A = K rows (s = ct2*32 + t5), 8 x K=16
            floatx16 sacc = {};
            #pragma unroll
            for (int ks = 0; ks < 8; ++ks) {
                short8 kfr = *(const short8*)&Ks[((ct2 * 32 + t5) * 16 + ((2 * ks + hh) ^ sw5)) * 8];
                sacc = __builtin_amdgcn_mfma_f32_32x32x16_bf16(kfr, qf2[ks], sacc, 0, 0, 0);
            }
            // ---- mask + exp2 + pack: reg r -> s_loc = (r&3) + 8*(r>>2) + 4*hh
            unsigned int w[8];
            float lsum = 0.0f;
            #pragma unroll
            for (int i = 0; i < 8; ++i) {
                const int r0i = 2 * i, r1i = 2 * i + 1;
                const int sl0 = (r0i & 3) + 8 * (r0i >> 2) + 4 * hh;
                float sa = sacc[r0i], sb = sacc[r1i];
                if (diag && (smin + sl0 > tg))     sa = -1e30f;
                if (diag && (smin + sl0 + 1 > tg)) sb = -1e30f;
                float p0 = EXP2(sa), p1 = EXP2(sb);
                lsum += p0 + p1;
                w[i] = pk2(p0, p1);
            }
            l_s += lsum;
            // ---- PV: 2 MFMAs (m: s-range 16m) x 4 d-blocks, A via permlane
            #pragma unroll
            for (int m = 0; m < 2; ++m) {
                union { short8 s8; unsigned int u[4]; } af;
#if __has_builtin(__builtin_amdgcn_permlane32_swap)
                uint2v x0 = __builtin_amdgcn_permlane32_swap(w[4 * m + 0], w[4 * m + 2], false, false);
                uint2v x1 = __builtin_amdgcn_permlane32_swap(w[4 * m + 1], w[4 * m + 3], false, false);
                af.u[0] = x0[0]; af.u[2] = x0[1];
                af.u[1] = x1[0]; af.u[3] = x1[1];
#else
                unsigned p0 = (unsigned)__shfl_xor((int)w[4 * m + 0], 32, 64);
                unsigned p1 = (unsigned)__shfl_xor((int)w[4 * m + 1], 32, 64);
                unsigned p2 = (unsigned)__shfl_xor((int)w[4 * m + 2], 32, 64);
                unsigned p3 = (unsigned)__shfl_xor((int)w[4 * m + 3], 32, 64);
                af.u[0] = hh ? p2 : w[4 * m + 0];
                af.u[1] = hh ? p3 : w[4 * m + 1];
                af.u[2] = hh ? w[4 * m + 2] : p0;
                af.u[3] = hh ? w[4 * m + 3] : p1;
#endif
                const int cs = ct2 * 4 + 2 * m + hh;
                #pragma unroll
                for (int b = 0; b < 4; ++b) {
                    const int d = b * 32 + t5;
                    short8 vfr = *(const short8*)&Vs[(d * 16 + (cs ^ (d & 7))) * 8];
                    oacc[b] = __builtin_amdgcn_mfma_f32_32x32x16_bf16(af.s8, vfr, oacc[b], 0, 0, 0);
                }
            }
        }
        __syncthreads();   // bar2: Ks/Vs reads done before next staging
    }

    // ---- epilogue: l[t] = own + partner half; redistribute per output row
    float lred = l_s + __shfl_xor(l_s, 32, 64);     // full row-sum for t = t5
    float linv = 1.0f / lred;
    #pragma unroll
    for (int r = 0; r < 16; ++r) {
        const int tl = (r & 3) + 8 * (r >> 2) + 4 * hh;
        float lv = __shfl(linv, tl, 64);            // lane tl holds t = tl
        const int rowg = wrow0 + tl;
        #pragma unroll
        for (int b = 0; b < 4; ++b)
            qkv[(size_t)rowg * QKV_W + h * HD + b * 32 + t5] = f2bf(oacc[b][r] * lv);
    }
}

extern "C" void kernel_launch(void* const* d_in, const int* in_sizes, int n_in,
                              void* d_out, int out_size, void* d_ws, size_t ws_size,
                              hipStream_t stream) {
    const int*   positions = (const int*)d_in[0];
    const float* hidden    = (const float*)d_in[1];
    const float* w_qkv     = (const float*)d_in[2];
    const float* w_o       = (const float*)d_in[3];
    const float* q_norm_w  = (const float*)d_in[4];
    const float* k_norm_w  = (const float*)d_in[5];
    float* out = (float*)d_out;

    unsigned short* qkvb   = (unsigned short*)d_ws;
    unsigned short* h_bf   = (unsigned short*)((char*)d_ws + ((size_t)32 << 20));
    unsigned short* Kp     = (unsigned short*)((char*)d_ws + ((size_t)32 << 20));
    unsigned short* Vp     = (unsigned short*)((char*)d_ws + ((size_t)40 << 20));
    unsigned short* wqkv_t = (unsigned short*)((char*)d_ws + ((size_t)48 << 20));
    unsigned short* wo_t   = (unsigned short*)((char*)d_ws + ((size_t)48 << 20));

    cvt_bf16<<<(T_TOK * H_DIM) / (256 * 8), 256, 0, stream>>>(hidden, h_bf);
    cvt_transpose<<<dim3(QKV_W / 64, H_DIM / 64), 256, 0, stream>>>(w_qkv, wqkv_t, H_DIM, QKV_W);
    // QKV: M=4096, N=4096, K=2048, BN=256 -> grid 16*16 = 256 blocks, 1/CU
    gemm8p<true, 256><<<dim3(256), 512, 0, stream>>>(
        h_bf, H_DIM, wqkv_t, H_DIM, qkvb, QKV_W, H_DIM, QKV_W / 256);
    rms_rope_bf16<<<T_TOK, 256, 0, stream>>>(qkvb, positions, q_norm_w, k_norm_w);
    kv_pack<<<dim3(T_TOK / 128, NKV), 256, 0, stream>>>(qkvb, Kp, Vp);
    cvt_transpose<<<dim3(H_DIM / 64, QS / 64), 256, 0, stream>>>(w_o, wo_t, QS, H_DIM);
    attn_mfma<<<512, 256, 0, stream>>>(qkvb, Kp, Vp);
    // WO: M=4096, N=2048, K=2048, BN=128 -> grid 16*16 = 256 blocks, 1/CU
    gemm8p<false, 128><<<dim3(256), 512, 0, stream>>>(
        qkvb, QKV_W, wo_t, QS, out, H_DIM, QS, H_DIM / 128);
}